// Round 2
// baseline (569.334 us; speedup 1.0000x reference)
//
#include <hip/hip_runtime.h>

// MovementPrunedLinear R5:
// - mpl_main: double-buffered LDS + counted-vmcnt prefetch pipeline (T3/T4-lite):
//   issue next K-step's global_load_lds before computing current; raw s_barrier +
//   s_waitcnt vmcnt(8) (never drain to 0 in steady state). B staged unconditionally
//   (keeps vmcnt countable); MFMA mask-gating unchanged. + bijective XCD swizzle (T1).
// - prep: grid-stride (3104 blocks instead of 12320) to probe per-block overhead.

#define BM 128
#define BN 128
#define BK 64

typedef __attribute__((ext_vector_type(8))) short bf16x8;
typedef __attribute__((ext_vector_type(4))) float f32x4;

__device__ __forceinline__ unsigned short f2bf(float f) {
    union { float f; unsigned u; } v; v.f = f;
    return (unsigned short)((v.u + 0x7FFFu + ((v.u >> 16) & 1u)) >> 16);
}

#define THRESH (-2.1972245773362196f)   // logit(0.1)

// ---------------- merged pre-pass (grid-stride) ----------------
// blocks [0,2048): X rows (stride 2048). blocks [2048,3072): W rows (stride 1024),
// skipping masked 32-blocks (never consumed: MFMA is bit-gated in mpl_main).
// blocks [3072, 3072+NB/4): pack mask bits, 4 nb per block (one per wave).
__global__ __launch_bounds__(256)
void prep(const float* __restrict__ X, const float* __restrict__ W,
          const float* __restrict__ scores,
          unsigned short* __restrict__ Xb, unsigned short* __restrict__ Wb,
          unsigned long long* __restrict__ mbits,
          int M, int N, int K) {
    const int b   = blockIdx.x;
    const int tid = threadIdx.x;
    const int KBlk = K >> 5;

    if (b < 2048) {
        for (int row = b; row < M; row += 2048) {
            const float* src = X + (long)row * K;
            unsigned short* dst = Xb + (long)row * K;
            for (int k = tid * 4; k < K; k += 1024) {
                const float4 a = *(const float4*)(src + k);
                ushort4 p;
                p.x = f2bf(a.x); p.y = f2bf(a.y); p.z = f2bf(a.z); p.w = f2bf(a.w);
                *(ushort4*)(dst + k) = p;
            }
        }
    } else if (b < 3072) {
        for (int row = b - 2048; row < N; row += 1024) {
            const float* src = W + (long)row * K;
            unsigned short* dst = Wb + (long)row * K;
            const float* srow = scores + (long)(row >> 5) * KBlk;
            for (int k = tid * 4; k < K; k += 1024) {
                if (srow[k >> 5] > THRESH) {          // uniform across 8-lane groups
                    const float4 a = *(const float4*)(src + k);
                    ushort4 p;
                    p.x = f2bf(a.x); p.y = f2bf(a.y); p.z = f2bf(a.z); p.w = f2bf(a.w);
                    *(ushort4*)(dst + k) = p;
                }
            }
        }
    } else {
        // mask pack: requires KBlk == 128 (guarded in launcher)
        const int nb = (b - 3072) * 4 + (tid >> 6);
        const int l  = tid & 63;
        const unsigned long long b0 = __ballot(scores[(long)nb * KBlk + l] > THRESH);
        const unsigned long long b1 = __ballot(scores[(long)nb * KBlk + 64 + l] > THRESH);
        if (l == 0) { mbits[nb * 2] = b0; mbits[nb * 2 + 1] = b1; }
    }
}

// ---------------- main GEMM ----------------

__device__ __forceinline__ unsigned long long rfl64(unsigned long long v) {
    unsigned lo = __builtin_amdgcn_readfirstlane((unsigned)v);
    unsigned hi = __builtin_amdgcn_readfirstlane((unsigned)(v >> 32));
    return ((unsigned long long)hi << 32) | lo;
}

#define GLL16(g, l) __builtin_amdgcn_global_load_lds( \
    (const __attribute__((address_space(1))) void*)(g), \
    (__attribute__((address_space(3))) void*)(l), 16, 0, 0)

// 8 loads per K-step: 4 A-rows-groups + 4 B-nb-groups (unconditional so vmcnt is countable)
#define STAGE(sAbuf, sBbuf, ko) do { \
    GLL16(gA + 0L * 32 * K2 + (ko), (sAbuf) + 0 * 4096 + ldso); \
    GLL16(gA + 1L * 32 * K2 + (ko), (sAbuf) + 1 * 4096 + ldso); \
    GLL16(gA + 2L * 32 * K2 + (ko), (sAbuf) + 2 * 4096 + ldso); \
    GLL16(gA + 3L * 32 * K2 + (ko), (sAbuf) + 3 * 4096 + ldso); \
    GLL16(gB + 0L * 32 * K2 + (ko), (sBbuf) + 0 * 4096 + ldso); \
    GLL16(gB + 1L * 32 * K2 + (ko), (sBbuf) + 1 * 4096 + ldso); \
    GLL16(gB + 2L * 32 * K2 + (ko), (sBbuf) + 2 * 4096 + ldso); \
    GLL16(gB + 3L * 32 * K2 + (ko), (sBbuf) + 3 * 4096 + ldso); \
} while (0)

__global__ __launch_bounds__(256)
void mpl_main(const unsigned short* __restrict__ Xb,   // [M,K] bf16
              const unsigned short* __restrict__ Wb,   // [N,K] bf16 (masked blocks stale/unused)
              const float* __restrict__ bias,
              const unsigned long long* __restrict__ mb, // [N/32][2]
              float* __restrict__ out, int M, int N, int K)
{
    // Row = BK bf16 = 128 B = 8 chunks of 16 B. LDS slot (r, c') holds global
    // chunk c'^(r&7) (XOR swizzle via permuted global fetch; GLL dest is fixed).
    __shared__ unsigned short sA0[BM * BK];   // 16 KB each, dbuf = 64 KB total
    __shared__ unsigned short sB0[BN * BK];
    __shared__ unsigned short sA1[BM * BK];
    __shared__ unsigned short sB1[BN * BK];

    const int tid  = threadIdx.x;
    const int lane = tid & 63;
    const int wave = tid >> 6;

    // bijective XCD swizzle: contiguous grid chunk per XCD -> A-panel L2 reuse
    const int nwg = gridDim.x;
    int L = blockIdx.x;
    if ((nwg & 7) == 0) L = (L & 7) * (nwg >> 3) + (L >> 3);
    const int nbx = N / BN;
    const int bx = L % nbx;
    const int by = L / nbx;

    const int m0   = by * BM;
    const int n0   = bx * BN;
    const int wm   = (wave & 1) * 64;
    const int wn   = (wave >> 1) * 64;
    const long K2  = (long)K * 2;

    // per-nb mask words (scalarized)
    const int nbb = n0 >> 5;
    unsigned long long mlo[4], mhi[4];
#pragma unroll
    for (int i = 0; i < 4; i++) {
        mlo[i] = rfl64(mb[(nbb + i) * 2]);
        mhi[i] = rfl64(mb[(nbb + i) * 2 + 1]);
    }

    f32x4 acc[4][4];
#pragma unroll
    for (int i = 0; i < 4; i++)
#pragma unroll
        for (int j = 0; j < 4; j++)
            acc[i][j] = (f32x4){0.f, 0.f, 0.f, 0.f};

    // staging geometry: lane covers row (32i + tid>>3), swizzled chunk (tid&7)^((tid>>3)&7)
    const int r8   = tid >> 3;                               // 0..31
    const int cswz = ((tid & 7) ^ ((tid >> 3) & 7)) * 16;    // byte offset in row
    const char* gA = (const char*)Xb + (long)(m0 + r8) * K2 + cswz;
    const char* gB = (const char*)Wb + (long)(n0 + r8) * K2 + cswz;
    char* sA0c = (char*)sA0;
    char* sB0c = (char*)sB0;
    char* sA1c = (char*)sA1;
    char* sB1c = (char*)sB1;
    const int ldso = wave * 1024;

    // fragment geometry
    const int fr   = lane & 15;
    const int cxor = lane & 7;
    const int kqc  = lane >> 4;          // 0..3
    const int rowA = wm + fr;            // + mi*16
    const int rowB = wn + fr;            // + ni*16

    // prologue: stage step 0 into buffer 0
    STAGE(sA0c, sB0c, 0L);

#pragma unroll 2
    for (int s = 0; s < 64; ++s) {
        // issue next step's loads into the other buffer, then wait for THIS
        // step's 8 loads (the 8 just issued stay in flight across the barrier)
        if (s < 63) {
            const long konext = (long)(s + 1) * 128;
            if (s & 1) STAGE(sA0c, sB0c, konext);
            else       STAGE(sA1c, sB1c, konext);
            asm volatile("s_waitcnt vmcnt(8)" ::: "memory");
        } else {
            asm volatile("s_waitcnt vmcnt(0)" ::: "memory");
        }
        __builtin_amdgcn_s_barrier();
        __builtin_amdgcn_sched_barrier(0);

        const char* cA = (s & 1) ? sA1c : sA0c;
        const char* cB = (s & 1) ? sB1c : sB0c;

        // pair bits for this step (k32 blocks 2s, 2s+1)
        const int hq = s & 31;
        const unsigned p0 = (unsigned)(((s & 32) ? mhi[0] : mlo[0]) >> (2 * hq)) & 3;
        const unsigned p1 = (unsigned)(((s & 32) ? mhi[1] : mlo[1]) >> (2 * hq)) & 3;
        const unsigned p2 = (unsigned)(((s & 32) ? mhi[2] : mlo[2]) >> (2 * hq)) & 3;
        const unsigned p3 = (unsigned)(((s & 32) ? mhi[3] : mlo[3]) >> (2 * hq)) & 3;
        const unsigned plo = (wave >> 1) ? p2 : p0;   // this wave's nb for ni 0,1
        const unsigned phi = (wave >> 1) ? p3 : p1;   // ni 2,3

        if (plo | phi) {
#pragma unroll
            for (int kbl = 0; kbl < 2; ++kbl) {
                if (!(((plo | phi) >> kbl) & 1)) continue;
                const int boff = ((kqc | (kbl << 2)) ^ cxor) * 16;

                bf16x8 af[4];
#pragma unroll
                for (int mi = 0; mi < 4; mi++)
                    af[mi] = *(const bf16x8*)(cA + (rowA + mi * 16) * 128 + boff);

                if ((plo >> kbl) & 1) {
                    const bf16x8 bf0 = *(const bf16x8*)(cB + (rowB + 0)  * 128 + boff);
                    const bf16x8 bf1 = *(const bf16x8*)(cB + (rowB + 16) * 128 + boff);
#pragma unroll
                    for (int mi = 0; mi < 4; mi++) {
                        acc[mi][0] = __builtin_amdgcn_mfma_f32_16x16x32_bf16(af[mi], bf0, acc[mi][0], 0, 0, 0);
                        acc[mi][1] = __builtin_amdgcn_mfma_f32_16x16x32_bf16(af[mi], bf1, acc[mi][1], 0, 0, 0);
                    }
                }
                if ((phi >> kbl) & 1) {
                    const bf16x8 bf2 = *(const bf16x8*)(cB + (rowB + 32) * 128 + boff);
                    const bf16x8 bf3 = *(const bf16x8*)(cB + (rowB + 48) * 128 + boff);
#pragma unroll
                    for (int mi = 0; mi < 4; mi++) {
                        acc[mi][2] = __builtin_amdgcn_mfma_f32_16x16x32_bf16(af[mi], bf2, acc[mi][2], 0, 0, 0);
                        acc[mi][3] = __builtin_amdgcn_mfma_f32_16x16x32_bf16(af[mi], bf3, acc[mi][3], 0, 0, 0);
                    }
                }
            }
        }
        __builtin_amdgcn_sched_barrier(0);
        __builtin_amdgcn_s_barrier();   // no wave may overwrite this buffer until all read it
    }

    // epilogue: C/D col=lane&15 (n), row=(lane>>4)*4+reg (m)
    const int cn = lane & 15;
    const int rq = (lane >> 4) * 4;
#pragma unroll
    for (int ni = 0; ni < 4; ni++) {
        const int n = n0 + wn + ni * 16 + cn;
        const float b = bias[n];
#pragma unroll
        for (int mi = 0; mi < 4; mi++) {
#pragma unroll
            for (int r = 0; r < 4; r++) {
                const int m = m0 + wm + mi * 16 + rq + r;
                out[(long)m * N + n] = acc[mi][ni][r] + b;
            }
        }
    }
}

// ---------------- fallback (R1 kernel) ----------------

#define FBK 32
#define LDSS (FBK + 8)
__global__ __launch_bounds__(256, 2)
void mpl_gemm_fb(const float* __restrict__ X, const float* __restrict__ W,
                 const float* __restrict__ bias, const float* __restrict__ scores,
                 float* __restrict__ out, int M, int N, int K)
{
    __shared__ unsigned short sA[BM * LDSS];
    __shared__ unsigned short sB[BN * LDSS];
    const int tid = threadIdx.x;
    const int m0 = blockIdx.y * BM, n0 = blockIdx.x * BN;
    const int wave = tid >> 6, lane = tid & 63;
    const int wm = (wave & 1) * 64, wn = (wave >> 1) * 64;
    const int kblocks = K >> 5;
    f32x4 acc[4][4];
#pragma unroll
    for (int i = 0; i < 4; i++)
#pragma unroll
        for (int j = 0; j < 4; j++) acc[i][j] = (f32x4){0.f,0.f,0.f,0.f};
    int srow[4], sc4[4], snb[4];
#pragma unroll
    for (int i = 0; i < 4; i++) {
        int f = tid + 256 * i;
        srow[i] = f >> 3; sc4[i] = f & 7; snb[i] = (n0 + srow[i]) >> 5;
    }
    for (int k0 = 0; k0 < K; k0 += FBK) {
        const int kb = k0 >> 5;
#pragma unroll
        for (int i = 0; i < 4; i++) {
            const float4 v = *(const float4*)(X + (long)(m0 + srow[i]) * K + k0 + sc4[i] * 4);
            ushort4 p; p.x = f2bf(v.x); p.y = f2bf(v.y); p.z = f2bf(v.z); p.w = f2bf(v.w);
            *(ushort4*)&sA[srow[i] * LDSS + sc4[i] * 4] = p;
        }
#pragma unroll
        for (int i = 0; i < 4; i++) {
            const float msk = (scores[snb[i] * kblocks + kb] > THRESH) ? 1.0f : 0.0f;
            const float4 v = *(const float4*)(W + (long)(n0 + srow[i]) * K + k0 + sc4[i] * 4);
            ushort4 p; p.x = f2bf(v.x*msk); p.y = f2bf(v.y*msk); p.z = f2bf(v.z*msk); p.w = f2bf(v.w*msk);
            *(ushort4*)&sB[srow[i] * LDSS + sc4[i] * 4] = p;
        }
        __syncthreads();
        const int fr = lane & 15, kq = (lane >> 4) * 8;
        bf16x8 af[4], bfr[4];
#pragma unroll
        for (int mi = 0; mi < 4; mi++) af[mi] = *(const bf16x8*)&sA[(wm + mi*16 + fr) * LDSS + kq];
#pragma unroll
        for (int ni = 0; ni < 4; ni++) bfr[ni] = *(const bf16x8*)&sB[(wn + ni*16 + fr) * LDSS + kq];
#pragma unroll
        for (int mi = 0; mi < 4; mi++)
#pragma unroll
            for (int ni = 0; ni < 4; ni++)
                acc[mi][ni] = __builtin_amdgcn_mfma_f32_16x16x32_bf16(af[mi], bfr[ni], acc[mi][ni], 0,0,0);
        __syncthreads();
    }
    const int cn = lane & 15, rq = (lane >> 4) * 4;
#pragma unroll
    for (int ni = 0; ni < 4; ni++) {
        const int n = n0 + wn + ni * 16 + cn;
        const float b = bias[n];
#pragma unroll
        for (int mi = 0; mi < 4; mi++)
#pragma unroll
            for (int r = 0; r < 4; r++)
                out[(long)(m0 + wm + mi*16 + rq + r) * N + n] = acc[mi][ni][r] + b;
    }
}

extern "C" void kernel_launch(void* const* d_in, const int* in_sizes, int n_in,
                              void* d_out, int out_size, void* d_ws, size_t ws_size,
                              hipStream_t stream) {
    const float* X      = (const float*)d_in[0];
    const float* W      = (const float*)d_in[1];
    const float* bias   = (const float*)d_in[2];
    const float* scores = (const float*)d_in[3];
    float* out          = (float*)d_out;

    const int N = in_sizes[2];            // 4096
    const int K = in_sizes[1] / N;        // 4096
    const int M = in_sizes[0] / K;        // 8192
    const int KB = K >> 5;                // 128
    const int NB = N >> 5;                // 128

    const size_t mk2 = (size_t)M * K * 2;
    const size_t nk2 = (size_t)N * K * 2;
    const size_t need = mk2 + nk2 + (size_t)NB * 16;

    if (ws_size >= need && KB == 128 && (M % 128) == 0 && (N % 128) == 0 &&
        (K % 1024) == 0 && (NB % 4) == 0) {
        unsigned short* Xb = (unsigned short*)d_ws;
        unsigned short* Wb = (unsigned short*)((char*)d_ws + mk2);
        unsigned long long* mbits = (unsigned long long*)((char*)d_ws + mk2 + nk2);

        prep<<<3072 + NB / 4, 256, 0, stream>>>(X, W, scores, Xb, Wb, mbits, M, N, K);

        mpl_main<<<dim3((N / BN) * (M / BM)), dim3(256), 0, stream>>>(Xb, Wb, bias, mbits, out, M, N, K);
    } else {
        dim3 grid(N / BN, M / BM);
        mpl_gemm_fb<<<grid, dim3(256), 0, stream>>>(X, W, bias, scores, out, M, N, K);
    }
}

// Round 3
// 549.296 us; speedup vs baseline: 1.0365x; 1.0365x over previous
//
#include <hip/hip_runtime.h>

// MovementPrunedLinear R6:
// - 2D grid restored (x-fastest => XCD k owns B-columns {k,k+8,k+16,k+24} = 4MB,
//   L2-resident for whole kernel; R5's row-chunk swizzle broke this: FETCH 303->800MB).
// - counted-vmcnt double-buffer pipeline kept (deconfounded test).
// - masked B pairs: global_load_lds source redirected to gA (same offset, L2-hot)
//   so vmcnt stays exactly 8/step without fetching masked Wb from HBM.
// - prep unchanged (grid-stride; residual ~235us invariant to prep structure).

#define BM 128
#define BN 128
#define BK 64

typedef __attribute__((ext_vector_type(8))) short bf16x8;
typedef __attribute__((ext_vector_type(4))) float f32x4;

__device__ __forceinline__ unsigned short f2bf(float f) {
    union { float f; unsigned u; } v; v.f = f;
    return (unsigned short)((v.u + 0x7FFFu + ((v.u >> 16) & 1u)) >> 16);
}

#define THRESH (-2.1972245773362196f)   // logit(0.1)

// ---------------- merged pre-pass (grid-stride) ----------------
__global__ __launch_bounds__(256)
void prep(const float* __restrict__ X, const float* __restrict__ W,
          const float* __restrict__ scores,
          unsigned short* __restrict__ Xb, unsigned short* __restrict__ Wb,
          unsigned long long* __restrict__ mbits,
          int M, int N, int K) {
    const int b   = blockIdx.x;
    const int tid = threadIdx.x;
    const int KBlk = K >> 5;

    if (b < 2048) {
        for (int row = b; row < M; row += 2048) {
            const float* src = X + (long)row * K;
            unsigned short* dst = Xb + (long)row * K;
            for (int k = tid * 4; k < K; k += 1024) {
                const float4 a = *(const float4*)(src + k);
                ushort4 p;
                p.x = f2bf(a.x); p.y = f2bf(a.y); p.z = f2bf(a.z); p.w = f2bf(a.w);
                *(ushort4*)(dst + k) = p;
            }
        }
    } else if (b < 3072) {
        for (int row = b - 2048; row < N; row += 1024) {
            const float* src = W + (long)row * K;
            unsigned short* dst = Wb + (long)row * K;
            const float* srow = scores + (long)(row >> 5) * KBlk;
            for (int k = tid * 4; k < K; k += 1024) {
                if (srow[k >> 5] > THRESH) {          // uniform across 8-lane groups
                    const float4 a = *(const float4*)(src + k);
                    ushort4 p;
                    p.x = f2bf(a.x); p.y = f2bf(a.y); p.z = f2bf(a.z); p.w = f2bf(a.w);
                    *(ushort4*)(dst + k) = p;
                }
            }
        }
    } else {
        // mask pack: requires KBlk == 128 (guarded in launcher)
        const int nb = (b - 3072) * 4 + (tid >> 6);
        const int l  = tid & 63;
        const unsigned long long b0 = __ballot(scores[(long)nb * KBlk + l] > THRESH);
        const unsigned long long b1 = __ballot(scores[(long)nb * KBlk + 64 + l] > THRESH);
        if (l == 0) { mbits[nb * 2] = b0; mbits[nb * 2 + 1] = b1; }
    }
}

// ---------------- main GEMM ----------------

__device__ __forceinline__ unsigned long long rfl64(unsigned long long v) {
    unsigned lo = __builtin_amdgcn_readfirstlane((unsigned)v);
    unsigned hi = __builtin_amdgcn_readfirstlane((unsigned)(v >> 32));
    return ((unsigned long long)hi << 32) | lo;
}

#define GLL16(g, l) __builtin_amdgcn_global_load_lds( \
    (const __attribute__((address_space(1))) void*)(g), \
    (__attribute__((address_space(3))) void*)(l), 16, 0, 0)

// pair bits (2 bits = k32 blocks 2s,2s+1) for nb-slot i at K-step s
#define PB(i, s) ((unsigned)((((s) & 32) ? mhi[i] : mlo[i]) >> (2 * ((s) & 31))) & 3)

// 8 loads per K-step: 4 A-groups + 4 B-nb-groups. Masked B pair -> source
// redirected to the matching gA address (valid + L2-hot; LDS slot never read).
#define STAGE(sAbuf, sBbuf, ko, q0, q1, q2, q3) do { \
    const char* b0_ = (q0) ? gB : gA; \
    const char* b1_ = (q1) ? gB : gA; \
    const char* b2_ = (q2) ? gB : gA; \
    const char* b3_ = (q3) ? gB : gA; \
    GLL16(gA  + 0L * 32 * K2 + (ko), (sAbuf) + 0 * 4096 + ldso); \
    GLL16(gA  + 1L * 32 * K2 + (ko), (sAbuf) + 1 * 4096 + ldso); \
    GLL16(gA  + 2L * 32 * K2 + (ko), (sAbuf) + 2 * 4096 + ldso); \
    GLL16(gA  + 3L * 32 * K2 + (ko), (sAbuf) + 3 * 4096 + ldso); \
    GLL16(b0_ + 0L * 32 * K2 + (ko), (sBbuf) + 0 * 4096 + ldso); \
    GLL16(b1_ + 1L * 32 * K2 + (ko), (sBbuf) + 1 * 4096 + ldso); \
    GLL16(b2_ + 2L * 32 * K2 + (ko), (sBbuf) + 2 * 4096 + ldso); \
    GLL16(b3_ + 3L * 32 * K2 + (ko), (sBbuf) + 3 * 4096 + ldso); \
} while (0)

__global__ __launch_bounds__(256)
void mpl_main(const unsigned short* __restrict__ Xb,   // [M,K] bf16
              const unsigned short* __restrict__ Wb,   // [N,K] bf16 (masked blocks stale/unused)
              const float* __restrict__ bias,
              const unsigned long long* __restrict__ mb, // [N/32][2]
              float* __restrict__ out, int M, int N, int K)
{
    // Row = BK bf16 = 128 B = 8 chunks of 16 B. LDS slot (r, c') holds global
    // chunk c'^(r&7) (XOR swizzle via permuted global fetch; GLL dest is fixed).
    __shared__ unsigned short sA0[BM * BK];   // 16 KB each, dbuf = 64 KB total
    __shared__ unsigned short sB0[BN * BK];
    __shared__ unsigned short sA1[BM * BK];
    __shared__ unsigned short sB1[BN * BK];

    const int tid  = threadIdx.x;
    const int lane = tid & 63;
    const int wave = tid >> 6;
    const int m0   = blockIdx.y * BM;
    const int n0   = blockIdx.x * BN;
    const int wm   = (wave & 1) * 64;
    const int wn   = (wave >> 1) * 64;
    const long K2  = (long)K * 2;

    // per-nb mask words (scalarized)
    const int nbb = n0 >> 5;
    unsigned long long mlo[4], mhi[4];
#pragma unroll
    for (int i = 0; i < 4; i++) {
        mlo[i] = rfl64(mb[(nbb + i) * 2]);
        mhi[i] = rfl64(mb[(nbb + i) * 2 + 1]);
    }

    f32x4 acc[4][4];
#pragma unroll
    for (int i = 0; i < 4; i++)
#pragma unroll
        for (int j = 0; j < 4; j++)
            acc[i][j] = (f32x4){0.f, 0.f, 0.f, 0.f};

    // staging geometry: lane covers row (32i + tid>>3), swizzled chunk (tid&7)^((tid>>3)&7)
    const int r8   = tid >> 3;                               // 0..31
    const int cswz = ((tid & 7) ^ ((tid >> 3) & 7)) * 16;    // byte offset in row
    const char* gA = (const char*)Xb + (long)(m0 + r8) * K2 + cswz;
    const char* gB = (const char*)Wb + (long)(n0 + r8) * K2 + cswz;
    char* sA0c = (char*)sA0;
    char* sB0c = (char*)sB0;
    char* sA1c = (char*)sA1;
    char* sB1c = (char*)sB1;
    const int ldso = wave * 1024;

    // fragment geometry
    const int fr   = lane & 15;
    const int cxor = lane & 7;
    const int kqc  = lane >> 4;          // 0..3
    const int rowA = wm + fr;            // + mi*16
    const int rowB = wn + fr;            // + ni*16

    // prologue: stage step 0 into buffer 0
    unsigned p0 = PB(0, 0), p1 = PB(1, 0), p2 = PB(2, 0), p3 = PB(3, 0);
    STAGE(sA0c, sB0c, 0L, p0, p1, p2, p3);

#pragma unroll 2
    for (int s = 0; s < 64; ++s) {
        const unsigned c0 = p0, c1 = p1, c2 = p2, c3 = p3;   // bits for step s
        // issue next step's loads into the other buffer, then wait for THIS
        // step's 8 loads (the 8 just issued stay in flight across the barrier)
        if (s < 63) {
            p0 = PB(0, s + 1); p1 = PB(1, s + 1); p2 = PB(2, s + 1); p3 = PB(3, s + 1);
            const long konext = (long)(s + 1) * 128;
            if (s & 1) STAGE(sA0c, sB0c, konext, p0, p1, p2, p3);
            else       STAGE(sA1c, sB1c, konext, p0, p1, p2, p3);
            asm volatile("s_waitcnt vmcnt(8)" ::: "memory");
        } else {
            asm volatile("s_waitcnt vmcnt(0)" ::: "memory");
        }
        __builtin_amdgcn_s_barrier();
        __builtin_amdgcn_sched_barrier(0);

        const char* cA = (s & 1) ? sA1c : sA0c;
        const char* cB = (s & 1) ? sB1c : sB0c;

        const unsigned plo = (wave >> 1) ? c2 : c0;   // this wave's nb for ni 0,1
        const unsigned phi = (wave >> 1) ? c3 : c1;   // ni 2,3

        if (plo | phi) {
#pragma unroll
            for (int kbl = 0; kbl < 2; ++kbl) {
                if (!(((plo | phi) >> kbl) & 1)) continue;
                const int boff = ((kqc | (kbl << 2)) ^ cxor) * 16;

                bf16x8 af[4];
#pragma unroll
                for (int mi = 0; mi < 4; mi++)
                    af[mi] = *(const bf16x8*)(cA + (rowA + mi * 16) * 128 + boff);

                if ((plo >> kbl) & 1) {
                    const bf16x8 bf0 = *(const bf16x8*)(cB + (rowB + 0)  * 128 + boff);
                    const bf16x8 bf1 = *(const bf16x8*)(cB + (rowB + 16) * 128 + boff);
#pragma unroll
                    for (int mi = 0; mi < 4; mi++) {
                        acc[mi][0] = __builtin_amdgcn_mfma_f32_16x16x32_bf16(af[mi], bf0, acc[mi][0], 0, 0, 0);
                        acc[mi][1] = __builtin_amdgcn_mfma_f32_16x16x32_bf16(af[mi], bf1, acc[mi][1], 0, 0, 0);
                    }
                }
                if ((phi >> kbl) & 1) {
                    const bf16x8 bf2 = *(const bf16x8*)(cB + (rowB + 32) * 128 + boff);
                    const bf16x8 bf3 = *(const bf16x8*)(cB + (rowB + 48) * 128 + boff);
#pragma unroll
                    for (int mi = 0; mi < 4; mi++) {
                        acc[mi][2] = __builtin_amdgcn_mfma_f32_16x16x32_bf16(af[mi], bf2, acc[mi][2], 0, 0, 0);
                        acc[mi][3] = __builtin_amdgcn_mfma_f32_16x16x32_bf16(af[mi], bf3, acc[mi][3], 0, 0, 0);
                    }
                }
            }
        }
        __builtin_amdgcn_sched_barrier(0);
        __builtin_amdgcn_s_barrier();   // no wave may overwrite this buffer until all read it
    }

    // epilogue: C/D col=lane&15 (n), row=(lane>>4)*4+reg (m)
    const int cn = lane & 15;
    const int rq = (lane >> 4) * 4;
#pragma unroll
    for (int ni = 0; ni < 4; ni++) {
        const int n = n0 + wn + ni * 16 + cn;
        const float b = bias[n];
#pragma unroll
        for (int mi = 0; mi < 4; mi++) {
#pragma unroll
            for (int r = 0; r < 4; r++) {
                const int m = m0 + wm + mi * 16 + rq + r;
                out[(long)m * N + n] = acc[mi][ni][r] + b;
            }
        }
    }
}

// ---------------- fallback (R1 kernel) ----------------

#define FBK 32
#define LDSS (FBK + 8)
__global__ __launch_bounds__(256, 2)
void mpl_gemm_fb(const float* __restrict__ X, const float* __restrict__ W,
                 const float* __restrict__ bias, const float* __restrict__ scores,
                 float* __restrict__ out, int M, int N, int K)
{
    __shared__ unsigned short sA[BM * LDSS];
    __shared__ unsigned short sB[BN * LDSS];
    const int tid = threadIdx.x;
    const int m0 = blockIdx.y * BM, n0 = blockIdx.x * BN;
    const int wave = tid >> 6, lane = tid & 63;
    const int wm = (wave & 1) * 64, wn = (wave >> 1) * 64;
    const int kblocks = K >> 5;
    f32x4 acc[4][4];
#pragma unroll
    for (int i = 0; i < 4; i++)
#pragma unroll
        for (int j = 0; j < 4; j++) acc[i][j] = (f32x4){0.f,0.f,0.f,0.f};
    int srow[4], sc4[4], snb[4];
#pragma unroll
    for (int i = 0; i < 4; i++) {
        int f = tid + 256 * i;
        srow[i] = f >> 3; sc4[i] = f & 7; snb[i] = (n0 + srow[i]) >> 5;
    }
    for (int k0 = 0; k0 < K; k0 += FBK) {
        const int kb = k0 >> 5;
#pragma unroll
        for (int i = 0; i < 4; i++) {
            const float4 v = *(const float4*)(X + (long)(m0 + srow[i]) * K + k0 + sc4[i] * 4);
            ushort4 p; p.x = f2bf(v.x); p.y = f2bf(v.y); p.z = f2bf(v.z); p.w = f2bf(v.w);
            *(ushort4*)&sA[srow[i] * LDSS + sc4[i] * 4] = p;
        }
#pragma unroll
        for (int i = 0; i < 4; i++) {
            const float msk = (scores[snb[i] * kblocks + kb] > THRESH) ? 1.0f : 0.0f;
            const float4 v = *(const float4*)(W + (long)(n0 + srow[i]) * K + k0 + sc4[i] * 4);
            ushort4 p; p.x = f2bf(v.x*msk); p.y = f2bf(v.y*msk); p.z = f2bf(v.z*msk); p.w = f2bf(v.w*msk);
            *(ushort4*)&sB[srow[i] * LDSS + sc4[i] * 4] = p;
        }
        __syncthreads();
        const int fr = lane & 15, kq = (lane >> 4) * 8;
        bf16x8 af[4], bfr[4];
#pragma unroll
        for (int mi = 0; mi < 4; mi++) af[mi] = *(const bf16x8*)&sA[(wm + mi*16 + fr) * LDSS + kq];
#pragma unroll
        for (int ni = 0; ni < 4; ni++) bfr[ni] = *(const bf16x8*)&sB[(wn + ni*16 + fr) * LDSS + kq];
#pragma unroll
        for (int mi = 0; mi < 4; mi++)
#pragma unroll
            for (int ni = 0; ni < 4; ni++)
                acc[mi][ni] = __builtin_amdgcn_mfma_f32_16x16x32_bf16(af[mi], bfr[ni], acc[mi][ni], 0,0,0);
        __syncthreads();
    }
    const int cn = lane & 15, rq = (lane >> 4) * 4;
#pragma unroll
    for (int ni = 0; ni < 4; ni++) {
        const int n = n0 + wn + ni * 16 + cn;
        const float b = bias[n];
#pragma unroll
        for (int mi = 0; mi < 4; mi++)
#pragma unroll
            for (int r = 0; r < 4; r++)
                out[(long)(m0 + wm + mi*16 + rq + r) * N + n] = acc[mi][ni][r] + b;
    }
}

extern "C" void kernel_launch(void* const* d_in, const int* in_sizes, int n_in,
                              void* d_out, int out_size, void* d_ws, size_t ws_size,
                              hipStream_t stream) {
    const float* X      = (const float*)d_in[0];
    const float* W      = (const float*)d_in[1];
    const float* bias   = (const float*)d_in[2];
    const float* scores = (const float*)d_in[3];
    float* out          = (float*)d_out;

    const int N = in_sizes[2];            // 4096
    const int K = in_sizes[1] / N;        // 4096
    const int M = in_sizes[0] / K;        // 8192
    const int KB = K >> 5;                // 128
    const int NB = N >> 5;                // 128

    const size_t mk2 = (size_t)M * K * 2;
    const size_t nk2 = (size_t)N * K * 2;
    const size_t need = mk2 + nk2 + (size_t)NB * 16;

    if (ws_size >= need && KB == 128 && (M % 128) == 0 && (N % 128) == 0 &&
        (K % 1024) == 0 && (NB % 4) == 0) {
        unsigned short* Xb = (unsigned short*)d_ws;
        unsigned short* Wb = (unsigned short*)((char*)d_ws + mk2);
        unsigned long long* mbits = (unsigned long long*)((char*)d_ws + mk2 + nk2);

        prep<<<3072 + NB / 4, 256, 0, stream>>>(X, W, scores, Xb, Wb, mbits, M, N, K);

        dim3 grid(N / BN, M / BM);
        mpl_main<<<grid, dim3(256), 0, stream>>>(Xb, Wb, bias, mbits, out, M, N, K);
    } else {
        dim3 grid(N / BN, M / BM);
        mpl_gemm_fb<<<grid, dim3(256), 0, stream>>>(X, W, bias, scores, out, M, N, K);
    }
}